// Round 1
// baseline (398.486 us; speedup 1.0000x reference)
//
#include <hip/hip_runtime.h>
#include <cfloat>
#include <math.h>

#define N_OBJ 8
#define N_PTS 2048
#define KNN   10
#define TOLC  0.01f

// ---- order-preserving float <-> uint for atomicMin on signed floats ----
__device__ __forceinline__ unsigned int enc_f(float f) {
    unsigned int u = __float_as_uint(f);
    return (u & 0x80000000u) ? ~u : (u | 0x80000000u);
}
__device__ __forceinline__ float dec_f(unsigned int e) {
    unsigned int u = (e & 0x80000000u) ? (e & 0x7fffffffu) : ~e;
    return __uint_as_float(u);
}

// Kernel 1: per-point transform. Every thread redundantly computes
// M = inv(T_plane) @ T_est[b] in double (cheap: ~200 f64 ops, closer to the
// numpy reference than an fp32 adjugate). Stores x as float4(x,y,z,|x|^2),
// normals as float4, and seeds SD[b,p] = enc(z).
__global__ void k_transform(const float* __restrict__ pts,
                            const float* __restrict__ T_est,
                            const float* __restrict__ T_plane,
                            float4* __restrict__ X,
                            float4* __restrict__ NR,
                            unsigned int* __restrict__ SD) {
    int gid = blockIdx.x * blockDim.x + threadIdx.x;
    if (gid >= N_OBJ * N_PTS) return;
    int b = gid >> 11;

    double m[16];
#pragma unroll
    for (int i = 0; i < 16; i++) m[i] = (double)T_plane[i];
    double inv[16];
    inv[0]  =  m[5]*m[10]*m[15] - m[5]*m[11]*m[14] - m[9]*m[6]*m[15] + m[9]*m[7]*m[14] + m[13]*m[6]*m[11] - m[13]*m[7]*m[10];
    inv[4]  = -m[4]*m[10]*m[15] + m[4]*m[11]*m[14] + m[8]*m[6]*m[15] - m[8]*m[7]*m[14] - m[12]*m[6]*m[11] + m[12]*m[7]*m[10];
    inv[8]  =  m[4]*m[9]*m[15]  - m[4]*m[11]*m[13] - m[8]*m[5]*m[15] + m[8]*m[7]*m[13] + m[12]*m[5]*m[11] - m[12]*m[7]*m[9];
    inv[12] = -m[4]*m[9]*m[14]  + m[4]*m[10]*m[13] + m[8]*m[5]*m[14] - m[8]*m[6]*m[13] - m[12]*m[5]*m[10] + m[12]*m[6]*m[9];
    inv[1]  = -m[1]*m[10]*m[15] + m[1]*m[11]*m[14] + m[9]*m[2]*m[15] - m[9]*m[3]*m[14] - m[13]*m[2]*m[11] + m[13]*m[3]*m[10];
    inv[5]  =  m[0]*m[10]*m[15] - m[0]*m[11]*m[14] - m[8]*m[2]*m[15] + m[8]*m[3]*m[14] + m[12]*m[2]*m[11] - m[12]*m[3]*m[10];
    inv[9]  = -m[0]*m[9]*m[15]  + m[0]*m[11]*m[13] + m[8]*m[1]*m[15] - m[8]*m[3]*m[13] - m[12]*m[1]*m[11] + m[12]*m[3]*m[9];
    inv[13] =  m[0]*m[9]*m[14]  - m[0]*m[10]*m[13] - m[8]*m[1]*m[14] + m[8]*m[2]*m[13] + m[12]*m[1]*m[10] - m[12]*m[2]*m[9];
    inv[2]  =  m[1]*m[6]*m[15]  - m[1]*m[7]*m[14]  - m[5]*m[2]*m[15] + m[5]*m[3]*m[14] + m[13]*m[2]*m[7]  - m[13]*m[3]*m[6];
    inv[6]  = -m[0]*m[6]*m[15]  + m[0]*m[7]*m[14]  + m[4]*m[2]*m[15] - m[4]*m[3]*m[14] - m[12]*m[2]*m[7]  + m[12]*m[3]*m[6];
    inv[10] =  m[0]*m[5]*m[15]  - m[0]*m[7]*m[13]  - m[4]*m[1]*m[15] + m[4]*m[3]*m[13] + m[12]*m[1]*m[7]  - m[12]*m[3]*m[5];
    inv[14] = -m[0]*m[5]*m[14]  + m[0]*m[6]*m[13]  + m[4]*m[1]*m[14] - m[4]*m[2]*m[13] - m[12]*m[1]*m[6]  + m[12]*m[2]*m[5];
    inv[3]  = -m[1]*m[6]*m[11]  + m[1]*m[7]*m[10]  + m[5]*m[2]*m[11] - m[5]*m[3]*m[10] - m[9]*m[2]*m[7]   + m[9]*m[3]*m[6];
    inv[7]  =  m[0]*m[6]*m[11]  - m[0]*m[7]*m[10]  - m[4]*m[2]*m[11] + m[4]*m[3]*m[10] + m[8]*m[2]*m[7]   - m[8]*m[3]*m[6];
    inv[11] = -m[0]*m[5]*m[11]  + m[0]*m[7]*m[9]   + m[4]*m[1]*m[11] - m[4]*m[3]*m[9]  - m[8]*m[1]*m[7]   + m[8]*m[3]*m[5];
    inv[15] =  m[0]*m[5]*m[10]  - m[0]*m[6]*m[9]   - m[4]*m[1]*m[10] + m[4]*m[2]*m[9]  + m[8]*m[1]*m[6]   - m[8]*m[2]*m[5];
    double det  = m[0]*inv[0] + m[1]*inv[4] + m[2]*inv[8] + m[3]*inv[12];
    double rdet = 1.0 / det;

    const float* Te = T_est + b * 16;
    double M[12];
#pragma unroll
    for (int i = 0; i < 3; i++)
#pragma unroll
        for (int j = 0; j < 4; j++) {
            double s = 0.0;
#pragma unroll
            for (int kk = 0; kk < 4; kk++) s += inv[i*4+kk] * rdet * (double)Te[kk*4+j];
            M[i*4+j] = s;
        }

    const float* pp = pts + (size_t)gid * 6;
    double px = pp[0], py = pp[1], pz = pp[2];
    float nx = pp[3], ny = pp[4], nz = pp[5];
    float x = (float)(M[0]*px + M[1]*py + M[2]*pz  + M[3]);
    float y = (float)(M[4]*px + M[5]*py + M[6]*pz  + M[7]);
    float z = (float)(M[8]*px + M[9]*py + M[10]*pz + M[11]);
    float sq = fmaf(x, x, fmaf(y, y, z * z));
    X[gid]  = make_float4(x, y, z, sq);
    NR[gid] = make_float4(nx, ny, nz, 0.0f);
    SD[gid] = enc_f(z);   // seed min with the plane-distance term z
}

// Kernel 2: one block per (object-pair, p-tile). block = 256 threads (one p
// each); object o's 2048 points staged in 32KB LDS; all lanes scan the same q
// (LDS broadcast, conflict-free). Sorted 10-entry top-k in registers (fully
// unrolled -> stays in VGPRs). Inside test needs only sign(dot(n_q, x_q-x_p)).
__global__ void __launch_bounds__(256) k_pairs(const float4* __restrict__ X,
                                               const float4* __restrict__ NR,
                                               unsigned int* __restrict__ SD) {
    __shared__ float4 XO[N_PTS];   // 32 KiB
    int bx   = blockIdx.x;
    int pair = bx >> 3;
    int tile = bx & 7;
    int b  = pair / 7;
    int oi = pair % 7;
    int o  = oi + (oi >= b ? 1 : 0);
    int tid = threadIdx.x;

    for (int i = tid; i < N_PTS; i += 256) XO[i] = X[o * N_PTS + i];
    __syncthreads();

    int p = tile * 256 + tid;
    float4 xp = X[b * N_PTS + p];

    float td[KNN];
    int   ti[KNN];
#pragma unroll
    for (int j = 0; j < KNN; j++) { td[j] = FLT_MAX; ti[j] = 0; }
    float thr = FLT_MAX;

    for (int q = 0; q < N_PTS; q++) {
        float4 xq = XO[q];
        float dx = xq.x - xp.x;
        float dy = xq.y - xp.y;
        float dz = xq.z - xp.z;
        float c  = fmaf(dx, dx, fmaf(dy, dy, dz * dz));
        if (c < thr) {
            // sorted insert (ascending), fully unrolled, reads-before-writes
#pragma unroll
            for (int j = KNN - 1; j >= 1; --j) {
                bool lo  = c < td[j - 1];
                float nv = lo ? td[j - 1] : c;
                int   ni = lo ? ti[j - 1] : q;
                bool  wr = c < td[j];
                td[j] = wr ? nv : td[j];
                ti[j] = wr ? ni : ti[j];
            }
            if (c < td[0]) { td[0] = c; ti[0] = q; }
            thr = td[KNN - 1];
        }
    }

    // inside test on the 10 nearest: sign(dot(n_q, x_q - x_p)) > 0
    int cnt = 0;
#pragma unroll
    for (int j = 0; j < KNN; j++) {
        int qi = ti[j];
        float4 xq = XO[qi];
        float4 nq = NR[o * N_PTS + qi];
        float s = nq.x * (xq.x - xp.x) + nq.y * (xq.y - xp.y) + nq.z * (xq.z - xp.z);
        cnt += (s > 0.0f) ? 1 : 0;
    }
    float d0 = sqrtf(fmaxf(td[0], 0.0f));
    if (cnt > 8) d0 = -d0;           // sum(insides) > k*0.8 = 8  ->  >= 9
    atomicMin(&SD[b * N_PTS + p], enc_f(d0));
}

// Kernel 3: decode and emit both outputs (concatenated: signed_distance then
// intersects as 0.0/1.0 floats).
__global__ void k_final(const unsigned int* __restrict__ SD,
                        float* __restrict__ out) {
    int gid = blockIdx.x * blockDim.x + threadIdx.x;
    if (gid >= N_OBJ * N_PTS) return;
    float sd = dec_f(SD[gid]);
    out[gid] = sd;
    out[N_OBJ * N_PTS + gid] = (sd < -TOLC) ? 1.0f : 0.0f;
}

extern "C" void kernel_launch(void* const* d_in, const int* in_sizes, int n_in,
                              void* d_out, int out_size, void* d_ws, size_t ws_size,
                              hipStream_t stream) {
    const float* pts     = (const float*)d_in[0];   // (8,2048,6)
    const float* T_est   = (const float*)d_in[1];   // (8,4,4)
    const float* T_plane = (const float*)d_in[2];   // (4,4)
    // d_in[3] is k == 10, hardcoded as KNN

    // workspace layout: X (256KB) | NR (256KB) | SD (64KB)
    float4*       X  = (float4*)d_ws;
    float4*       NR = X + N_OBJ * N_PTS;
    unsigned int* SD = (unsigned int*)(NR + N_OBJ * N_PTS);

    float* out = (float*)d_out;

    k_transform<<<(N_OBJ * N_PTS) / 256, 256, 0, stream>>>(pts, T_est, T_plane, X, NR, SD);
    k_pairs<<<N_OBJ * (N_OBJ - 1) * (N_PTS / 256), 256, 0, stream>>>(X, NR, SD);
    k_final<<<(N_OBJ * N_PTS) / 256, 256, 0, stream>>>(SD, out);
}